// Round 1
// baseline (437.141 us; speedup 1.0000x reference)
//
#include <hip/hip_runtime.h>
#include <cstdint>

#define S_TOKENS 16384
#define NEXP     8
#define CAP      2560
#define BLK      256
#define NBLK     (S_TOKENS / BLK)   // 64
#define NWAVE    (BLK / 64)         // 4

// Kernel 1: per-token top1 + softmax prob + within-block per-expert rank,
// plus per-block per-expert counts. Deterministic (ballot-based, no atomics).
__global__ __launch_bounds__(BLK) void k_route(const float* __restrict__ in,
                                               float* __restrict__ prob,
                                               int* __restrict__ packed,
                                               int* __restrict__ block_counts) {
    int t = blockIdx.x * BLK + threadIdx.x;
    const float4* p4 = reinterpret_cast<const float4*>(in + (size_t)t * NEXP);
    float4 a = p4[0], b = p4[1];
    float x[8] = {a.x, a.y, a.z, a.w, b.x, b.y, b.z, b.w};

    // argmax, first-max wins (matches jnp.argmax)
    float m = x[0]; int idx = 0;
#pragma unroll
    for (int i = 1; i < 8; ++i) {
        if (x[i] > m) { m = x[i]; idx = i; }
    }
    // softmax prob of the top expert = 1 / sum(exp(x - max))
    float s = 0.f;
#pragma unroll
    for (int i = 0; i < 8; ++i) s += __expf(x[i] - m);
    float p = 1.0f / s;

    // per-wave ballots: which lanes picked expert e
    unsigned long long bal[NEXP];
#pragma unroll
    for (int e = 0; e < NEXP; ++e) bal[e] = __ballot(idx == e);

    int lane = threadIdx.x & 63;
    int wv   = threadIdx.x >> 6;

    __shared__ int wcnt[NWAVE][NEXP];
    if (lane < NEXP) wcnt[wv][lane] = __popcll(bal[lane]);
    __syncthreads();

    unsigned long long ltmask = (1ULL << lane) - 1ULL;  // lanes below me
    int r = __popcll(bal[idx] & ltmask);
#pragma unroll
    for (int w = 0; w < NWAVE; ++w)
        if (w < wv) r += wcnt[w][idx];

    prob[t]   = p;
    packed[t] = (r << 3) | idx;   // rank_in_block < 256, expert in low 3 bits

    if (threadIdx.x < NEXP) {
        int c = 0;
#pragma unroll
        for (int w = 0; w < NWAVE; ++w) c += wcnt[w][threadIdx.x];
        block_counts[blockIdx.x * NEXP + threadIdx.x] = c;
    }
}

// Kernel 2: exclusive scan of block counts per expert (64 blocks x 8 experts,
// trivial serial scan per expert).
__global__ void k_scan(const int* __restrict__ block_counts,
                       int* __restrict__ block_offs) {
    int e = threadIdx.x;
    if (e < NEXP) {
        int acc = 0;
        for (int b = 0; b < NBLK; ++b) {
            block_offs[b * NEXP + e] = acc;
            acc += block_counts[b * NEXP + e];
        }
    }
}

// Kernel 3: scatter the 16384 nonzeros into the (already zeroed) output.
__global__ __launch_bounds__(BLK) void k_scatter(const float* __restrict__ prob,
                                                 const int* __restrict__ packed,
                                                 const int* __restrict__ block_offs,
                                                 float* __restrict__ out,
                                                 size_t mask_base) {
    int t = blockIdx.x * BLK + threadIdx.x;
    int pk  = packed[t];
    int idx = pk & 7;
    int r   = pk >> 3;
    int g = block_offs[blockIdx.x * NEXP + idx] + r;
    if (g < CAP) {
        size_t o = ((size_t)t * NEXP + idx) * CAP + (size_t)g;
        out[o] = prob[t];               // combine_weights
        out[mask_base + o] = 1.0f;      // sec_mask (bool as 0/1 float)
    }
}

extern "C" void kernel_launch(void* const* d_in, const int* in_sizes, int n_in,
                              void* d_out, int out_size, void* d_ws, size_t ws_size,
                              hipStream_t stream) {
    const float* in = (const float*)d_in[0];
    float* out = (float*)d_out;

    char* ws = (char*)d_ws;
    float* prob   = (float*)(ws);                    // 16384 * 4 = 64 KB
    int*   packed = (int*)(ws + (64 << 10));         // 64 KB
    int*   bcnt   = (int*)(ws + (128 << 10));        // 2 KB
    int*   boff   = (int*)(ws + (130 << 10));        // 2 KB

    // Zero the entire output (both tensors) — this is the bandwidth floor.
    hipMemsetAsync(d_out, 0, (size_t)out_size * sizeof(float), stream);

    k_route<<<NBLK, BLK, 0, stream>>>(in, prob, packed, bcnt);
    k_scan<<<1, 64, 0, stream>>>(bcnt, boff);

    size_t mask_base = (size_t)out_size / 2;  // second output starts here
    k_scatter<<<NBLK, BLK, 0, stream>>>(prob, packed, boff, out, mask_base);
}